// Round 7
// baseline (444.076 us; speedup 1.0000x reference)
//
#include <hip/hip_runtime.h>
#include <hip/hip_fp16.h>
#include <math.h>

#define B_    8
#define S_    8192
#define DIN   64
#define DM    256
#define NS    32
#define NL    4
#define PIPE  192            // pipeline tokens per block (64 warm + 128 out)
#define TOUT  128
#define NWARM 64
#define HIST  16             // scan window; a^17 <= 0.35^17 ~ 7e-9
#define NBLK  (B_ * S_ / TOUT)   // 512

// ---- fp32 precomputed-weight offsets (Wf) ----
#define OFF_G   0            // [64][64]  in_w^T in_w
#define OFF_GX  4096         // [64]      in_w^T in_b
#define OFF_G0  4160         // [1]       ||in_b||^2 (pad to 4224)
#define OFF_WY  4224         // [4][64][32]  (Bws_l . in_w)^T  (c-major)
#define OFF_WU  12416        // [4][64][32]  (Cw_l^T in_w)^T   (c-major)
#define OFF_P   20608        // [6][32][32]  Bws_m.Cw_lp
#define OFF_R   26752        // [10][32][32] Cw_m^T Cw_lp
#define OFF_CY  36992        // [4][32]
#define OFF_CU  37120        // [4][32]
#define OFF_TX  37248        // [4][64]
#define OFF_TV  37504        // [10][32]
#define OFF_CT  37824        // [4]
#define OFF_CC  37828        // [4]
#define OFF_AV  37832        // [4][32]
#define PRE_N   37960

// ---- packed-fp16 weight offsets (Wh, u32 units) ----
#define HOFF_G   0           // [32][64]
#define HOFF_GX  2048        // [32]
#define HOFF_WY  2080        // [4][32][32]
#define HOFF_WU  6176        // [4][32][32]
#define HOFF_P   10272       // [6][16][32]
#define HOFF_R   13344       // [10][16][32]
#define HOFF_TX  18464       // [4][32]
#define HOFF_TV  18592       // [10][16]
#define WH_N     18752

#define WS_WH    40960       // float offset of Wh region in ws
#define WS_PART  65536       // float offset of part[512][193]

// ---- LDS u32 layout: x[192][33] | D[192][17] | slot[192][17] ----
#define XSTR    33
#define SSTR    17
#define LOFF_D  6336
#define LOFF_SLOT 9600
#define LDSN    12864        // u32 -> 51,456 B -> 3 blocks/CU
#define PSTR    35           // reduce scratch stride (floats)

typedef _Float16 h2_t __attribute__((ext_vector_type(2)));

__device__ __forceinline__ float h2f(ushort u) { return __half2float(__ushort_as_half(u)); }
__device__ __forceinline__ ushort f2h(float f) { return __half_as_ushort(__float2half(f)); }
__device__ __forceinline__ void unpack2(uint w, float& a, float& b) {
  a = h2f((ushort)(w & 0xffffu)); b = h2f((ushort)(w >> 16));
}
__device__ __forceinline__ uint pack2(float a, float b) {
  return (uint)f2h(a) | ((uint)f2h(b) << 16);
}
__device__ __forceinline__ float fdot2h(uint w, uint v, float c) {
  return __builtin_amdgcn_fdot2(__builtin_bit_cast(h2_t, w),
                                __builtin_bit_cast(h2_t, v), c, false);
}

// acc[32] += W.x  (W packed pairs over c, n-fast; x = packed LDS row)
__device__ __forceinline__ void mv64h(const uint* __restrict__ Wp,
                                      const uint* __restrict__ xrow, float acc[32]) {
  #pragma unroll 4
  for (int c2 = 0; c2 < 32; ++c2) {
    const uint xp = xrow[c2];
    const uint* W0 = Wp + c2 * 32;
    #pragma unroll
    for (int n = 0; n < 32; ++n) acc[n] = fdot2h(W0[n], xp, acc[n]);
  }
}
// acc[32] += M.s  (M packed pairs over m, n-fast; s = packed regs)
__device__ __forceinline__ void mv32h(const uint* __restrict__ Mp,
                                      const uint sp[16], float acc[32]) {
  #pragma unroll
  for (int m2 = 0; m2 < 16; ++m2) {
    const uint* M0 = Mp + m2 * 32;
    #pragma unroll
    for (int n = 0; n < 32; ++n) acc[n] = fdot2h(M0[n], sp[m2], acc[n]);
  }
}
__device__ __forceinline__ float dotx(const uint* __restrict__ vp,
                                      const uint* __restrict__ xrow, float c) {
  #pragma unroll 8
  for (int c2 = 0; c2 < 32; ++c2) c = fdot2h(vp[c2], xrow[c2], c);
  return c;
}
__device__ __forceinline__ float dot16h(const uint* __restrict__ vp,
                                        const uint sp[16], float c) {
  #pragma unroll
  for (int m2 = 0; m2 < 16; ++m2) c = fdot2h(vp[m2], sp[m2], c);
  return c;
}

template<int L>
__device__ __forceinline__ uint (&pickS(uint (&s0)[16], uint (&s1)[16],
                                        uint (&s2)[16], uint (&s3)[16]))[16] {
  if constexpr (L == 0) return s0;
  else if constexpr (L == 1) return s1;
  else if constexpr (L == 2) return s2;
  else return s3;
}

// ---------------------------------------------------------------------------
// Prep: fused fp32 matrices (identical to round-6 version, verified).
// ---------------------------------------------------------------------------
__global__ void ssm_prep(const float* __restrict__ in_w, const float* __restrict__ in_b,
                         const float* __restrict__ logA,
                         const float* __restrict__ Bw, const float* __restrict__ Cw,
                         const float* __restrict__ Cb, const float* __restrict__ nsc,
                         float* __restrict__ Wf)
{
  const int t = blockIdx.x * 256 + threadIdx.x;
  if (t >= PRE_N) return;
  const int pm6[6]  = {1,2,2,3,3,3}, pl6[6] = {0,0,1,0,1,2};
  const int rm10[10] = {0,1,1,2,2,2,3,3,3,3}, rl10[10] = {0,0,1,0,1,2,0,1,2,3};
  float s = 0.f;
  if (t < OFF_GX) {
    const int i = t >> 6, jj = t & 63;
    for (int d = 0; d < DM; ++d) s = fmaf(in_w[d*64 + i], in_w[d*64 + jj], s);
  } else if (t < OFF_G0) {
    const int i = t - OFF_GX;
    for (int d = 0; d < DM; ++d) s = fmaf(in_w[d*64 + i], in_b[d], s);
  } else if (t < OFF_WY) {
    if (t == OFF_G0) { for (int d = 0; d < DM; ++d) s = fmaf(in_b[d], in_b[d], s); }
  } else if (t < OFF_WU) {
    const int r = t - OFF_WY, l = r >> 11, q = r & 2047, c = q >> 5, n = q & 31;
    for (int d = 0; d < DM; ++d)
      s = fmaf(Bw[(l*NS + n)*DM + d] * nsc[l*DM + d], in_w[d*64 + c], s);
  } else if (t < OFF_P) {
    const int r = t - OFF_WU, l = r >> 11, q = r & 2047, c = q >> 5, n = q & 31;
    for (int d = 0; d < DM; ++d)
      s = fmaf(Cw[(l*DM + d)*NS + n], in_w[d*64 + c], s);
  } else if (t < OFF_R) {
    const int r = t - OFF_P, pi = r >> 10, q = r & 1023, np = q >> 5, n = q & 31;
    const int m = pm6[pi], lp = pl6[pi];
    for (int d = 0; d < DM; ++d)
      s = fmaf(Bw[(m*NS + n)*DM + d] * nsc[m*DM + d], Cw[(lp*DM + d)*NS + np], s);
  } else if (t < OFF_CY) {
    const int r = t - OFF_R, ri = r >> 10, q = r & 1023, np = q >> 5, n = q & 31;
    const int m = rm10[ri], lp = rl10[ri];
    for (int d = 0; d < DM; ++d)
      s = fmaf(Cw[(m*DM + d)*NS + n], Cw[(lp*DM + d)*NS + np], s);
  } else if (t < OFF_CU) {
    const int r = t - OFF_CY, l = r >> 5, n = r & 31;
    for (int d = 0; d < DM; ++d) {
      float bs = in_b[d];
      for (int lp = 0; lp < l; ++lp) bs += Cb[lp*DM + d];
      s = fmaf(Bw[(l*NS + n)*DM + d] * nsc[l*DM + d], bs, s);
    }
  } else if (t < OFF_TX) {
    const int r = t - OFF_CU, l = r >> 5, n = r & 31;
    for (int d = 0; d < DM; ++d) {
      float bs = in_b[d];
      for (int lp = 0; lp < l; ++lp) bs += Cb[lp*DM + d];
      s = fmaf(Cw[(l*DM + d)*NS + n], bs, s);
    }
  } else if (t < OFF_TV) {
    const int r = t - OFF_TX, l = r >> 6, i = r & 63;
    for (int d = 0; d < DM; ++d) s = fmaf(Cb[l*DM + d], in_w[d*64 + i], s);
  } else if (t < OFF_CT) {
    const int r = t - OFF_TV, vi = r >> 5, np = r & 31;
    const int m = rm10[vi], lp = rl10[vi];
    for (int d = 0; d < DM; ++d)
      s = fmaf(Cb[m*DM + d], Cw[(lp*DM + d)*NS + np], s);
  } else if (t < OFF_CC) {
    const int l = t - OFF_CT;
    for (int d = 0; d < DM; ++d) {
      float bs = in_b[d];
      for (int lp = 0; lp < l; ++lp) bs += Cb[lp*DM + d];
      s = fmaf(Cb[l*DM + d], bs, s);
    }
  } else if (t < OFF_AV) {
    const int l = t - OFF_CC;
    for (int d = 0; d < DM; ++d) s = fmaf(Cb[l*DM + d], Cb[l*DM + d], s);
  } else {
    s = 1.0f / (1.0f + expf(-logA[t - OFF_AV]));
  }
  Wf[t] = s;
}

// ---------------------------------------------------------------------------
// Pack: fp32 fused matrices -> fp16 pairs for v_dot2_f32_f16.
// ---------------------------------------------------------------------------
__global__ void ssm_pack(const float* __restrict__ Wf, uint* __restrict__ Wh)
{
  const int t = blockIdx.x * 256 + threadIdx.x;
  if (t >= WH_N) return;
  float a, b;
  if (t < HOFF_GX) {
    const int c2 = t >> 6, i = t & 63;
    a = Wf[OFF_G + (2*c2)*64 + i]; b = Wf[OFF_G + (2*c2+1)*64 + i];
  } else if (t < HOFF_WY) {
    const int c2 = t - HOFF_GX;
    a = Wf[OFF_GX + 2*c2]; b = Wf[OFF_GX + 2*c2 + 1];
  } else if (t < HOFF_WU) {
    const int r = t - HOFF_WY, l = r >> 10, q = r & 1023, c2 = q >> 5, n = q & 31;
    a = Wf[OFF_WY + l*2048 + (2*c2)*32 + n]; b = Wf[OFF_WY + l*2048 + (2*c2+1)*32 + n];
  } else if (t < HOFF_P) {
    const int r = t - HOFF_WU, l = r >> 10, q = r & 1023, c2 = q >> 5, n = q & 31;
    a = Wf[OFF_WU + l*2048 + (2*c2)*32 + n]; b = Wf[OFF_WU + l*2048 + (2*c2+1)*32 + n];
  } else if (t < HOFF_R) {
    const int r = t - HOFF_P, pi = r >> 9, q = r & 511, m2 = q >> 5, n = q & 31;
    a = Wf[OFF_P + pi*1024 + (2*m2)*32 + n]; b = Wf[OFF_P + pi*1024 + (2*m2+1)*32 + n];
  } else if (t < HOFF_TX) {
    const int r = t - HOFF_R, ri = r >> 9, q = r & 511, m2 = q >> 5, n = q & 31;
    a = Wf[OFF_R + ri*1024 + (2*m2)*32 + n]; b = Wf[OFF_R + ri*1024 + (2*m2+1)*32 + n];
  } else if (t < HOFF_TV) {
    const int r = t - HOFF_TX, l = r >> 5, c2 = r & 31;
    a = Wf[OFF_TX + l*64 + 2*c2]; b = Wf[OFF_TX + l*64 + 2*c2 + 1];
  } else {
    const int r = t - HOFF_TV, vi = r >> 4, m2 = r & 15;
    a = Wf[OFF_TV + vi*32 + 2*m2]; b = Wf[OFF_TV + vi*32 + 2*m2 + 1];
  }
  Wh[t] = pack2(a, b);
}

// ---------------------------------------------------------------------------
// Per-layer body (L compile-time): y/D -> scan (or FIR) -> u/nq update.
// s-history lives in packed registers; one LDS slot reused per layer.
// ---------------------------------------------------------------------------
template<int L>
__device__ __forceinline__ void layer_body(
    const int j, const int ltok, uint* lds,
    const float* __restrict__ Wf, const uint* __restrict__ Wh,
    const float* __restrict__ Bb, float& nq,
    uint (&s0p)[16], uint (&s1p)[16], uint (&s2p)[16], uint (&s3p)[16])
{
  const float inv = 1.0f / (sqrtf(fmaxf(nq, 0.f)) * 0.0625f + 1e-8f);
  const uint* xrow = lds + j * XSTR;
  constexpr int RB = (L * (L + 1)) / 2;
  constexpr int PB = (L == 1) ? 0 : (L == 2) ? 1 : 3;
  uint (&sLp)[16] = pickS<L>(s0p, s1p, s2p, s3p);

  // y = CY + Wy.x + sum_lp P.s_lp ; D = valid ? inv*y + Bb : 0
  {
    float acc[32];
    #pragma unroll
    for (int n = 0; n < 32; ++n) acc[n] = Wf[OFF_CY + L*32 + n];
    mv64h(Wh + HOFF_WY + L*1024, xrow, acc);
    if constexpr (L > 0) mv32h(Wh + HOFF_P + (PB+0)*512, s0p, acc);
    if constexpr (L > 1) mv32h(Wh + HOFF_P + (PB+1)*512, s1p, acc);
    if constexpr (L > 2) mv32h(Wh + HOFF_P + (PB+2)*512, s2p, acc);
    uint* drow = lds + LOFF_D + j * SSTR;
    const bool valid = (ltok >= 0);
    #pragma unroll
    for (int m = 0; m < 16; ++m) {
      float v0 = valid ? fmaf(inv, acc[2*m],   Bb[L*32 + 2*m])   : 0.f;
      float v1 = valid ? fmaf(inv, acc[2*m+1], Bb[L*32 + 2*m+1]) : 0.f;
      drow[m] = pack2(v0, v1);
    }
  }
  __syncthreads();

  if constexpr (L < 3) {
    // windowed scan: thread (n, tg) produces s for 32 tokens
    const int n = j & 31, tg = j >> 5;
    const float a = Wf[OFF_AV + L*32 + n];
    const ushort* dh = (const ushort*)(lds + LOFF_D);
    ushort* sh = (ushort*)(lds + LOFF_SLOT);
    float carry = 0.f;
    int p = tg * 32 - HIST;
    #pragma unroll
    for (int k = 0; k < HIST; ++k, ++p) {
      float v = (p >= 0) ? h2f(dh[p*34 + n]) : 0.f;
      carry = fmaf(a, carry, v);
    }
    #pragma unroll
    for (int k = 0; k < 32; ++k, ++p) {
      carry = fmaf(a, carry, h2f(dh[p*34 + n]));
      sh[p*34 + n] = f2h(carry);
    }
    __syncthreads();
    #pragma unroll
    for (int m = 0; m < 16; ++m) sLp[m] = lds[LOFF_SLOT + j*SSTR + m];
  } else {
    // layer 3: owner-local Horner FIR over D, result packed in regs
    float s3[32];
    #pragma unroll
    for (int n = 0; n < 32; ++n) s3[n] = 0.f;
    if (j >= NWARM) {
      #pragma unroll 1
      for (int lag = HIST; lag >= 0; --lag) {
        const uint* row = lds + LOFF_D + (j - lag) * SSTR;
        #pragma unroll
        for (int m = 0; m < 16; ++m) {
          float v0, v1; unpack2(row[m], v0, v1);
          s3[2*m]   = fmaf(Wf[OFF_AV + 96 + 2*m],   s3[2*m],   v0);
          s3[2*m+1] = fmaf(Wf[OFF_AV + 96 + 2*m+1], s3[2*m+1], v1);
        }
      }
    }
    #pragma unroll
    for (int m = 0; m < 16; ++m) sLp[m] = pack2(s3[2*m], s3[2*m+1]);
  }

  // u = CU + Wu.x + sum R.s ; t ; nq += 2(u.s + t) + s^T R s + 2 tv.s + cc
  {
    float acc2[32];
    #pragma unroll
    for (int n = 0; n < 32; ++n) acc2[n] = Wf[OFF_CU + L*32 + n];
    mv64h(Wh + HOFF_WU + L*1024, xrow, acc2);
    float tl = Wf[OFF_CT + L];
    tl = dotx(Wh + HOFF_TX + L*32, xrow, tl);
    if constexpr (L > 0) { mv32h(Wh + HOFF_R + (RB+0)*512, s0p, acc2);
                           tl = dot16h(Wh + HOFF_TV + (RB+0)*16, s0p, tl); }
    if constexpr (L > 1) { mv32h(Wh + HOFF_R + (RB+1)*512, s1p, acc2);
                           tl = dot16h(Wh + HOFF_TV + (RB+1)*16, s1p, tl); }
    if constexpr (L > 2) { mv32h(Wh + HOFF_R + (RB+2)*512, s2p, acc2);
                           tl = dot16h(Wh + HOFF_TV + (RB+2)*16, s2p, tl); }
    float us = 0.f;
    #pragma unroll
    for (int m = 0; m < 16; ++m) {
      float a, b; unpack2(sLp[m], a, b);
      us = fmaf(acc2[2*m], a, us); us = fmaf(acc2[2*m+1], b, us);
    }
    float acc3[32];
    #pragma unroll
    for (int n = 0; n < 32; ++n) acc3[n] = 0.f;
    mv32h(Wh + HOFF_R + (RB+L)*512, sLp, acc3);
    float rss = 0.f;
    #pragma unroll
    for (int m = 0; m < 16; ++m) {
      float a, b; unpack2(sLp[m], a, b);
      rss = fmaf(acc3[2*m], a, rss); rss = fmaf(acc3[2*m+1], b, rss);
    }
    const float qs = dot16h(Wh + HOFF_TV + (RB+L)*16, sLp, 0.f);
    nq = nq + 2.f*(us + tl) + rss + 2.f*qs + Wf[OFF_CC + L];
  }
}

// ---------------------------------------------------------------------------
// Main kernel.
// ---------------------------------------------------------------------------
__global__ __launch_bounds__(PIPE, 3) void ssm_main(
    const float* __restrict__ x, const float* __restrict__ Wf,
    const uint* __restrict__ Wh, const float* __restrict__ Bb,
    float* __restrict__ part)
{
  extern __shared__ uint lds[];
  const int j = threadIdx.x;
  const int blk = blockIdx.x;
  const int bb = blk >> 6;
  const int s0base = (blk & 63) * TOUT;
  const int ltok = s0base - NWARM + j;

  // stage x -> fp16 LDS (coalesced)
  {
    const float4* xg4 = (const float4*)(x + (size_t)bb * S_ * DIN);
    #pragma unroll
    for (int k = 0; k < 16; ++k) {
      const int f = k * PIPE + j;
      const int tok = f >> 4, c4 = f & 15;
      const int lt = s0base - NWARM + tok;
      float4 v = make_float4(0.f, 0.f, 0.f, 0.f);
      if (lt >= 0) v = xg4[lt * 16 + c4];
      lds[tok * XSTR + 2*c4]     = pack2(v.x, v.y);
      lds[tok * XSTR + 2*c4 + 1] = pack2(v.z, v.w);
    }
  }
  __syncthreads();

  const uint* xrow = lds + j * XSTR;

  // nq0 = g0 + 2 gx.x + x^T G x
  float nq = Wf[OFF_G0];
  nq = fmaf(2.f, dotx(Wh + HOFF_GX, xrow, 0.f), nq);
  #pragma unroll 1
  for (int hh = 0; hh < 2; ++hh) {
    float a2[32];
    #pragma unroll
    for (int n = 0; n < 32; ++n) a2[n] = 0.f;
    #pragma unroll 4
    for (int c2 = 0; c2 < 32; ++c2) {
      const uint xp = xrow[c2];
      const uint* G0 = Wh + HOFF_G + c2*64 + 32*hh;
      #pragma unroll
      for (int n = 0; n < 32; ++n) a2[n] = fdot2h(G0[n], xp, a2[n]);
    }
    float hd = 0.f;
    #pragma unroll
    for (int m = 0; m < 16; ++m) {
      float a, b; unpack2(xrow[16*hh + m], a, b);
      hd = fmaf(a, a2[2*m], hd); hd = fmaf(b, a2[2*m+1], hd);
    }
    nq += hd;
  }

  uint s0p[16], s1p[16], s2p[16], s3p[16];
  layer_body<0>(j, ltok, lds, Wf, Wh, Bb, nq, s0p, s1p, s2p, s3p);
  layer_body<1>(j, ltok, lds, Wf, Wh, Bb, nq, s0p, s1p, s2p, s3p);
  layer_body<2>(j, ltok, lds, Wf, Wh, Bb, nq, s0p, s1p, s2p, s3p);
  layer_body<3>(j, ltok, lds, Wf, Wh, Bb, nq, s0p, s1p, s2p, s3p);

  const float r = 1.0f / (sqrtf(fmaxf(nq, 0.f)) * 0.0625f + 1e-8f);
  __syncthreads();   // all FIR D-reads done; LDS becomes reduce scratch

  float* pf = (float*)lds;
  const int jj = j - NWARM;

  // pass 0: [r, x0..31 * r]
  if (j >= NWARM) {
    pf[jj*PSTR] = r;
    const float4* xr4 = (const float4*)(x + ((size_t)bb * S_ + (size_t)ltok) * DIN);
    #pragma unroll
    for (int c4 = 0; c4 < 8; ++c4) {
      const float4 v = xr4[c4];
      pf[jj*PSTR + 1 + 4*c4] = v.x * r; pf[jj*PSTR + 2 + 4*c4] = v.y * r;
      pf[jj*PSTR + 3 + 4*c4] = v.z * r; pf[jj*PSTR + 4 + 4*c4] = v.w * r;
    }
  }
  __syncthreads();
  if (j < 33) { float s = 0.f; for (int k = 0; k < TOUT; ++k) s += pf[k*PSTR + j];
                part[blk*193 + j] = s; }
  __syncthreads();
  // pass 1: x32..63 * r
  if (j >= NWARM) {
    const float4* xr4 = (const float4*)(x + ((size_t)bb * S_ + (size_t)ltok) * DIN);
    #pragma unroll
    for (int c4 = 8; c4 < 16; ++c4) {
      const float4 v = xr4[c4];
      const int o = 4*c4 - 32;
      pf[jj*PSTR + o] = v.x * r; pf[jj*PSTR + o + 1] = v.y * r;
      pf[jj*PSTR + o + 2] = v.z * r; pf[jj*PSTR + o + 3] = v.w * r;
    }
  }
  __syncthreads();
  if (j < 32) { float s = 0.f; for (int k = 0; k < TOUT; ++k) s += pf[k*PSTR + j];
                part[blk*193 + 33 + j] = s; }
  __syncthreads();

#define SPASS(SARR, COLBASE)                                                  \
  if (j >= NWARM) {                                                           \
    _Pragma("unroll")                                                         \
    for (int m = 0; m < 16; ++m) {                                            \
      float a_, b_; unpack2(SARR[m], a_, b_);                                 \
      pf[jj*PSTR + 2*m] = a_ * r; pf[jj*PSTR + 2*m + 1] = b_ * r;             \
    }                                                                         \
  }                                                                           \
  __syncthreads();                                                            \
  if (j < 32) { float s_ = 0.f;                                               \
    for (int k = 0; k < TOUT; ++k) s_ += pf[k*PSTR + j];                      \
    part[blk*193 + (COLBASE) + j] = s_; }                                     \
  __syncthreads();

  SPASS(s0p, 65)
  SPASS(s1p, 97)
  SPASS(s2p, 129)
  SPASS(s3p, 161)
#undef SPASS
}

// ---------------------------------------------------------------------------
// Final: reduce partials, reconstruct 256-dim mean, classifier MLP.
// ---------------------------------------------------------------------------
__global__ __launch_bounds__(256) void ssm_final(
    const float* __restrict__ part,
    const float* __restrict__ in_w, const float* __restrict__ in_b,
    const float* __restrict__ Cw, const float* __restrict__ Cb,
    const float* __restrict__ fsc,
    const float* __restrict__ w1, const float* __restrict__ b1,
    const float* __restrict__ w2, const float* __restrict__ b2,
    float* __restrict__ out)
{
  const int b = blockIdx.x, t = threadIdx.x;
  __shared__ float red[193];
  __shared__ float meanv[DM];
  __shared__ float h1[DM];
  if (t < 193) {
    float s = 0.f;
    for (int k = 0; k < 64; ++k) s += part[(b*64 + k)*193 + t];
    red[t] = s;
  }
  __syncthreads();
  {
    const float rho = red[0];
    float m = in_b[t] * rho;
    #pragma unroll 4
    for (int i = 0; i < 64; ++i) m = fmaf(in_w[t*64 + i], red[1 + i], m);
    for (int l = 0; l < NL; ++l) {
      #pragma unroll 4
      for (int n = 0; n < 32; ++n)
        m = fmaf(Cw[(l*DM + t)*NS + n], red[65 + l*32 + n], m);
      m = fmaf(Cb[l*DM + t], rho, m);
    }
    meanv[t] = fsc[t] * m * (1.0f / (float)S_);
  }
  __syncthreads();
  {
    float z = b1[t];
    for (int e = 0; e < DM; ++e) z = fmaf(w1[t*DM + e], meanv[e], z);
    h1[t] = z / (1.0f + expf(-z));
  }
  __syncthreads();
  if (t < 10) {
    float lg = b2[t];
    for (int e = 0; e < DM; ++e) lg = fmaf(w2[t*DM + e], h1[e], lg);
    out[b*10 + t] = lg;
  }
}

// ---------------------------------------------------------------------------
extern "C" void kernel_launch(void* const* d_in, const int* in_sizes, int n_in,
                              void* d_out, int out_size, void* d_ws, size_t ws_size,
                              hipStream_t stream)
{
  const float* x    = (const float*)d_in[0];
  const float* in_w = (const float*)d_in[1];
  const float* in_b = (const float*)d_in[2];
  const float* logA = (const float*)d_in[3];
  const float* Bw   = (const float*)d_in[4];
  const float* Bb   = (const float*)d_in[5];
  const float* Cw   = (const float*)d_in[6];
  const float* Cb   = (const float*)d_in[7];
  const float* nsc  = (const float*)d_in[8];
  const float* fsc  = (const float*)d_in[9];
  const float* w1   = (const float*)d_in[10];
  const float* b1   = (const float*)d_in[11];
  const float* w2   = (const float*)d_in[12];
  const float* b2   = (const float*)d_in[13];
  float* out = (float*)d_out;
  float* wsf  = (float*)d_ws;
  uint*  Wh   = (uint*)(wsf + WS_WH);
  float* part = wsf + WS_PART;
  (void)in_sizes; (void)n_in; (void)out_size; (void)ws_size;

  ssm_prep<<<(PRE_N + 255) / 256, 256, 0, stream>>>(in_w, in_b, logA, Bw, Cw, Cb, nsc, wsf);
  ssm_pack<<<(WH_N + 255) / 256, 256, 0, stream>>>(wsf, Wh);
  ssm_main<<<NBLK, PIPE, LDSN * sizeof(uint), stream>>>(x, wsf, Wh, Bb, part);
  ssm_final<<<B_, 256, 0, stream>>>(part, in_w, in_b, Cw, Cb, fsc, w1, b1, w2, b2, out);
}

// Round 8
// 360.718 us; speedup vs baseline: 1.2311x; 1.2311x over previous
//
#include <hip/hip_runtime.h>
#include <hip/hip_fp16.h>
#include <math.h>

#define B_    8
#define S_    8192
#define DIN   64
#define DM    256
#define NS    32
#define NL    4
#define PIPE  192            // pipeline tokens per block (64 warm + 128 out)
#define TOUT  128
#define NWARM 64
#define HIST  16             // scan window; a^17 <= 0.35^17 ~ 7e-9
#define NBLK  (B_ * S_ / TOUT)   // 512

// ---- fp32 precomputed-weight offsets (Wf) ----
#define OFF_G   0            // [64][64]  in_w^T in_w
#define OFF_GX  4096         // [64]      in_w^T in_b
#define OFF_G0  4160         // [1]       ||in_b||^2 (pad to 4224)
#define OFF_WY  4224         // [4][64][32]  (Bws_l . in_w)^T  (c-major)
#define OFF_WU  12416        // [4][64][32]  (Cw_l^T in_w)^T   (c-major)
#define OFF_P   20608        // [6][32][32]  Bws_m.Cw_lp
#define OFF_R   26752        // [10][32][32] Cw_m^T Cw_lp
#define OFF_CY  36992        // [4][32]
#define OFF_CU  37120        // [4][32]
#define OFF_TX  37248        // [4][64]
#define OFF_TV  37504        // [10][32]
#define OFF_CT  37824        // [4]
#define OFF_CC  37828        // [4]
#define OFF_AV  37832        // [4][32]
#define PRE_N   37960

// ---- packed-fp16 weight offsets (Wh, u32 units) ----
#define HOFF_G   0           // [32][64]
#define HOFF_GX  2048        // [32]
#define HOFF_WY  2080        // [4][32][32]
#define HOFF_WU  6176        // [4][32][32]
#define HOFF_P   10272       // [6][16][32]
#define HOFF_R   13344       // [10][16][32]
#define HOFF_TX  18464       // [4][32]
#define HOFF_TV  18592       // [10][16]
#define WH_N     18752

#define WS_WH    40960       // float offset of Wh region in ws
#define WS_PART  65536       // float offset of part[512][193]

// ---- LDS u32 layout: x[192][33] | D[192][17] | slot[192][17] ----
#define XSTR    33
#define SSTR    17
#define LOFF_D  6336
#define LOFF_SLOT 9600
#define LDSN    12864        // u32 -> 51,456 B -> 3 blocks/CU
#define PSTR    35           // reduce scratch stride (floats)

typedef _Float16 h2_t __attribute__((ext_vector_type(2)));
typedef uint uv16 __attribute__((ext_vector_type(16)));   // spill-proof s-state

__device__ __forceinline__ float h2f(ushort u) { return __half2float(__ushort_as_half(u)); }
__device__ __forceinline__ ushort f2h(float f) { return __half_as_ushort(__float2half(f)); }
__device__ __forceinline__ void unpack2(uint w, float& a, float& b) {
  a = h2f((ushort)(w & 0xffffu)); b = h2f((ushort)(w >> 16));
}
__device__ __forceinline__ uint pack2(float a, float b) {
  return (uint)f2h(a) | ((uint)f2h(b) << 16);
}
__device__ __forceinline__ float fdot2h(uint w, uint v, float c) {
  return __builtin_amdgcn_fdot2(__builtin_bit_cast(h2_t, w),
                                __builtin_bit_cast(h2_t, v), c, false);
}

// acc[32] += W.x  (W packed pairs over c, n-fast; x = packed LDS row)
__device__ __forceinline__ void mv64h(const uint* __restrict__ Wp,
                                      const uint* __restrict__ xrow, float acc[32]) {
  #pragma unroll 4
  for (int c2 = 0; c2 < 32; ++c2) {
    const uint xp = xrow[c2];
    const uint* W0 = Wp + c2 * 32;
    #pragma unroll
    for (int n = 0; n < 32; ++n) acc[n] = fdot2h(W0[n], xp, acc[n]);
  }
}
// acc[32] += M.s  (M packed pairs over m, n-fast; s = packed vector regs)
__device__ __forceinline__ void mv32h(const uint* __restrict__ Mp,
                                      uv16 sp, float acc[32]) {
  #pragma unroll
  for (int m2 = 0; m2 < 16; ++m2) {
    const uint sv = sp[m2];
    const uint* M0 = Mp + m2 * 32;
    #pragma unroll
    for (int n = 0; n < 32; ++n) acc[n] = fdot2h(M0[n], sv, acc[n]);
  }
}
__device__ __forceinline__ float dotx(const uint* __restrict__ vp,
                                      const uint* __restrict__ xrow, float c) {
  #pragma unroll 8
  for (int c2 = 0; c2 < 32; ++c2) c = fdot2h(vp[c2], xrow[c2], c);
  return c;
}
__device__ __forceinline__ float dot16h(const uint* __restrict__ vp,
                                        uv16 sp, float c) {
  #pragma unroll
  for (int m2 = 0; m2 < 16; ++m2) c = fdot2h(vp[m2], sp[m2], c);
  return c;
}

// ---------------------------------------------------------------------------
// Prep: fused fp32 matrices (identical to round-6/7 version, verified).
// ---------------------------------------------------------------------------
__global__ void ssm_prep(const float* __restrict__ in_w, const float* __restrict__ in_b,
                         const float* __restrict__ logA,
                         const float* __restrict__ Bw, const float* __restrict__ Cw,
                         const float* __restrict__ Cb, const float* __restrict__ nsc,
                         float* __restrict__ Wf)
{
  const int t = blockIdx.x * 256 + threadIdx.x;
  if (t >= PRE_N) return;
  const int pm6[6]  = {1,2,2,3,3,3}, pl6[6] = {0,0,1,0,1,2};
  const int rm10[10] = {0,1,1,2,2,2,3,3,3,3}, rl10[10] = {0,0,1,0,1,2,0,1,2,3};
  float s = 0.f;
  if (t < OFF_GX) {
    const int i = t >> 6, jj = t & 63;
    for (int d = 0; d < DM; ++d) s = fmaf(in_w[d*64 + i], in_w[d*64 + jj], s);
  } else if (t < OFF_G0) {
    const int i = t - OFF_GX;
    for (int d = 0; d < DM; ++d) s = fmaf(in_w[d*64 + i], in_b[d], s);
  } else if (t < OFF_WY) {
    if (t == OFF_G0) { for (int d = 0; d < DM; ++d) s = fmaf(in_b[d], in_b[d], s); }
  } else if (t < OFF_WU) {
    const int r = t - OFF_WY, l = r >> 11, q = r & 2047, c = q >> 5, n = q & 31;
    for (int d = 0; d < DM; ++d)
      s = fmaf(Bw[(l*NS + n)*DM + d] * nsc[l*DM + d], in_w[d*64 + c], s);
  } else if (t < OFF_P) {
    const int r = t - OFF_WU, l = r >> 11, q = r & 2047, c = q >> 5, n = q & 31;
    for (int d = 0; d < DM; ++d)
      s = fmaf(Cw[(l*DM + d)*NS + n], in_w[d*64 + c], s);
  } else if (t < OFF_R) {
    const int r = t - OFF_P, pi = r >> 10, q = r & 1023, np = q >> 5, n = q & 31;
    const int m = pm6[pi], lp = pl6[pi];
    for (int d = 0; d < DM; ++d)
      s = fmaf(Bw[(m*NS + n)*DM + d] * nsc[m*DM + d], Cw[(lp*DM + d)*NS + np], s);
  } else if (t < OFF_CY) {
    const int r = t - OFF_R, ri = r >> 10, q = r & 1023, np = q >> 5, n = q & 31;
    const int m = rm10[ri], lp = rl10[ri];
    for (int d = 0; d < DM; ++d)
      s = fmaf(Cw[(m*DM + d)*NS + n], Cw[(lp*DM + d)*NS + np], s);
  } else if (t < OFF_CU) {
    const int r = t - OFF_CY, l = r >> 5, n = r & 31;
    for (int d = 0; d < DM; ++d) {
      float bs = in_b[d];
      for (int lp = 0; lp < l; ++lp) bs += Cb[lp*DM + d];
      s = fmaf(Bw[(l*NS + n)*DM + d] * nsc[l*DM + d], bs, s);
    }
  } else if (t < OFF_TX) {
    const int r = t - OFF_CU, l = r >> 5, n = r & 31;
    for (int d = 0; d < DM; ++d) {
      float bs = in_b[d];
      for (int lp = 0; lp < l; ++lp) bs += Cb[lp*DM + d];
      s = fmaf(Cw[(l*DM + d)*NS + n], bs, s);
    }
  } else if (t < OFF_TV) {
    const int r = t - OFF_TX, l = r >> 6, i = r & 63;
    for (int d = 0; d < DM; ++d) s = fmaf(Cb[l*DM + d], in_w[d*64 + i], s);
  } else if (t < OFF_CT) {
    const int r = t - OFF_TV, vi = r >> 5, np = r & 31;
    const int m = rm10[vi], lp = rl10[vi];
    for (int d = 0; d < DM; ++d)
      s = fmaf(Cb[m*DM + d], Cw[(lp*DM + d)*NS + np], s);
  } else if (t < OFF_CC) {
    const int l = t - OFF_CT;
    for (int d = 0; d < DM; ++d) {
      float bs = in_b[d];
      for (int lp = 0; lp < l; ++lp) bs += Cb[lp*DM + d];
      s = fmaf(Cb[l*DM + d], bs, s);
    }
  } else if (t < OFF_AV) {
    const int l = t - OFF_CC;
    for (int d = 0; d < DM; ++d) s = fmaf(Cb[l*DM + d], Cb[l*DM + d], s);
  } else {
    s = 1.0f / (1.0f + expf(-logA[t - OFF_AV]));
  }
  Wf[t] = s;
}

// ---------------------------------------------------------------------------
// Pack: fp32 fused matrices -> fp16 pairs for v_dot2_f32_f16.
// ---------------------------------------------------------------------------
__global__ void ssm_pack(const float* __restrict__ Wf, uint* __restrict__ Wh)
{
  const int t = blockIdx.x * 256 + threadIdx.x;
  if (t >= WH_N) return;
  float a, b;
  if (t < HOFF_GX) {
    const int c2 = t >> 6, i = t & 63;
    a = Wf[OFF_G + (2*c2)*64 + i]; b = Wf[OFF_G + (2*c2+1)*64 + i];
  } else if (t < HOFF_WY) {
    const int c2 = t - HOFF_GX;
    a = Wf[OFF_GX + 2*c2]; b = Wf[OFF_GX + 2*c2 + 1];
  } else if (t < HOFF_WU) {
    const int r = t - HOFF_WY, l = r >> 10, q = r & 1023, c2 = q >> 5, n = q & 31;
    a = Wf[OFF_WY + l*2048 + (2*c2)*32 + n]; b = Wf[OFF_WY + l*2048 + (2*c2+1)*32 + n];
  } else if (t < HOFF_P) {
    const int r = t - HOFF_WU, l = r >> 10, q = r & 1023, c2 = q >> 5, n = q & 31;
    a = Wf[OFF_WU + l*2048 + (2*c2)*32 + n]; b = Wf[OFF_WU + l*2048 + (2*c2+1)*32 + n];
  } else if (t < HOFF_R) {
    const int r = t - HOFF_P, pi = r >> 9, q = r & 511, m2 = q >> 5, n = q & 31;
    a = Wf[OFF_P + pi*1024 + (2*m2)*32 + n]; b = Wf[OFF_P + pi*1024 + (2*m2+1)*32 + n];
  } else if (t < HOFF_TX) {
    const int r = t - HOFF_R, ri = r >> 9, q = r & 511, m2 = q >> 5, n = q & 31;
    a = Wf[OFF_R + ri*1024 + (2*m2)*32 + n]; b = Wf[OFF_R + ri*1024 + (2*m2+1)*32 + n];
  } else if (t < HOFF_TV) {
    const int r = t - HOFF_TX, l = r >> 5, c2 = r & 31;
    a = Wf[OFF_TX + l*64 + 2*c2]; b = Wf[OFF_TX + l*64 + 2*c2 + 1];
  } else {
    const int r = t - HOFF_TV, vi = r >> 4, m2 = r & 15;
    a = Wf[OFF_TV + vi*32 + 2*m2]; b = Wf[OFF_TV + vi*32 + 2*m2 + 1];
  }
  Wh[t] = pack2(a, b);
}

// ---------------------------------------------------------------------------
// Per-layer body (L compile-time). s-state passed/returned BY VALUE as
// ext-vectors (SSA; cannot spill to scratch). All s-indexing fully unrolled.
// ---------------------------------------------------------------------------
template<int L>
__device__ __forceinline__ uv16 layer_body(
    const int j, const int ltok, uint* lds,
    const float* __restrict__ Wf, const uint* __restrict__ Wh,
    const float* __restrict__ Bb, float& nq,
    uv16 s0, uv16 s1, uv16 s2)
{
  const float inv = 1.0f / (sqrtf(fmaxf(nq, 0.f)) * 0.0625f + 1e-8f);
  const uint* xrow = lds + j * XSTR;
  constexpr int RB = (L * (L + 1)) / 2;
  constexpr int PB = (L == 1) ? 0 : (L == 2) ? 1 : 3;
  uv16 sL;

  // y = CY + Wy.x + sum_lp P.s_lp ; D = valid ? inv*y + Bb : 0
  {
    float acc[32];
    #pragma unroll
    for (int n = 0; n < 32; ++n) acc[n] = Wf[OFF_CY + L*32 + n];
    mv64h(Wh + HOFF_WY + L*1024, xrow, acc);
    if constexpr (L > 0) mv32h(Wh + HOFF_P + (PB+0)*512, s0, acc);
    if constexpr (L > 1) mv32h(Wh + HOFF_P + (PB+1)*512, s1, acc);
    if constexpr (L > 2) mv32h(Wh + HOFF_P + (PB+2)*512, s2, acc);
    uint* drow = lds + LOFF_D + j * SSTR;
    const bool valid = (ltok >= 0);
    #pragma unroll
    for (int m = 0; m < 16; ++m) {
      float v0 = valid ? fmaf(inv, acc[2*m],   Bb[L*32 + 2*m])   : 0.f;
      float v1 = valid ? fmaf(inv, acc[2*m+1], Bb[L*32 + 2*m+1]) : 0.f;
      drow[m] = pack2(v0, v1);
    }
  }
  __syncthreads();

  if constexpr (L < 3) {
    // windowed scan: thread (n, tg) produces s for 32 tokens
    const int n = j & 31, tg = j >> 5;
    const float a = Wf[OFF_AV + L*32 + n];
    const ushort* dh = (const ushort*)(lds + LOFF_D);
    ushort* sh = (ushort*)(lds + LOFF_SLOT);
    float carry = 0.f;
    int p = tg * 32 - HIST;
    #pragma unroll
    for (int k = 0; k < HIST; ++k, ++p) {
      float v = (p >= 0) ? h2f(dh[p*34 + n]) : 0.f;
      carry = fmaf(a, carry, v);
    }
    #pragma unroll
    for (int k = 0; k < 32; ++k, ++p) {
      carry = fmaf(a, carry, h2f(dh[p*34 + n]));
      sh[p*34 + n] = f2h(carry);
    }
    __syncthreads();
    #pragma unroll
    for (int m = 0; m < 16; ++m) sL[m] = lds[LOFF_SLOT + j*SSTR + m];
  } else {
    // layer 3: owner-local Horner FIR over D; result packed into vector regs
    float s3[32];
    #pragma unroll
    for (int n = 0; n < 32; ++n) s3[n] = 0.f;
    if (j >= NWARM) {
      #pragma unroll 1
      for (int lag = HIST; lag >= 0; --lag) {
        const uint* row = lds + LOFF_D + (j - lag) * SSTR;
        #pragma unroll
        for (int m = 0; m < 16; ++m) {
          float v0, v1; unpack2(row[m], v0, v1);
          s3[2*m]   = fmaf(Wf[OFF_AV + 96 + 2*m],   s3[2*m],   v0);
          s3[2*m+1] = fmaf(Wf[OFF_AV + 96 + 2*m+1], s3[2*m+1], v1);
        }
      }
    }
    #pragma unroll
    for (int m = 0; m < 16; ++m) sL[m] = pack2(s3[2*m], s3[2*m+1]);
  }

  // u = CU + Wu.x + sum R.s ; t ; nq += 2(u.s + t) + s^T R s + 2 tv.s + cc
  {
    float acc2[32];
    #pragma unroll
    for (int n = 0; n < 32; ++n) acc2[n] = Wf[OFF_CU + L*32 + n];
    mv64h(Wh + HOFF_WU + L*1024, xrow, acc2);
    float tl = Wf[OFF_CT + L];
    tl = dotx(Wh + HOFF_TX + L*32, xrow, tl);
    if constexpr (L > 0) { mv32h(Wh + HOFF_R + (RB+0)*512, s0, acc2);
                           tl = dot16h(Wh + HOFF_TV + (RB+0)*16, s0, tl); }
    if constexpr (L > 1) { mv32h(Wh + HOFF_R + (RB+1)*512, s1, acc2);
                           tl = dot16h(Wh + HOFF_TV + (RB+1)*16, s1, tl); }
    if constexpr (L > 2) { mv32h(Wh + HOFF_R + (RB+2)*512, s2, acc2);
                           tl = dot16h(Wh + HOFF_TV + (RB+2)*16, s2, tl); }
    float us = 0.f;
    #pragma unroll
    for (int m = 0; m < 16; ++m) {
      float a, b; unpack2(sL[m], a, b);
      us = fmaf(acc2[2*m], a, us); us = fmaf(acc2[2*m+1], b, us);
    }
    float acc3[32];
    #pragma unroll
    for (int n = 0; n < 32; ++n) acc3[n] = 0.f;
    mv32h(Wh + HOFF_R + (RB+L)*512, sL, acc3);
    float rss = 0.f;
    #pragma unroll
    for (int m = 0; m < 16; ++m) {
      float a, b; unpack2(sL[m], a, b);
      rss = fmaf(acc3[2*m], a, rss); rss = fmaf(acc3[2*m+1], b, rss);
    }
    const float qs = dot16h(Wh + HOFF_TV + (RB+L)*16, sL, 0.f);
    nq = nq + 2.f*(us + tl) + rss + 2.f*qs + Wf[OFF_CC + L];
  }
  return sL;
}

// ---------------------------------------------------------------------------
// s-partial reduce pass: write s*r columns, column-sum into part.
// ---------------------------------------------------------------------------
__device__ __forceinline__ void spass(uv16 s, float r, float* pf,
                                      int j, int jj, float* __restrict__ part,
                                      int colbase, int blk)
{
  if (j >= NWARM) {
    #pragma unroll
    for (int m = 0; m < 16; ++m) {
      float a, b; unpack2(s[m], a, b);
      pf[jj*PSTR + 2*m] = a * r; pf[jj*PSTR + 2*m + 1] = b * r;
    }
  }
  __syncthreads();
  if (j < 32) {
    float t = 0.f;
    for (int k = 0; k < TOUT; ++k) t += pf[k*PSTR + j];
    part[blk*193 + colbase + j] = t;
  }
  __syncthreads();
}

// ---------------------------------------------------------------------------
// Main kernel.
// ---------------------------------------------------------------------------
__global__ __launch_bounds__(PIPE, 3) void ssm_main(
    const float* __restrict__ x, const float* __restrict__ Wf,
    const uint* __restrict__ Wh, const float* __restrict__ Bb,
    float* __restrict__ part)
{
  extern __shared__ uint lds[];
  const int j = threadIdx.x;
  const int blk = blockIdx.x;
  const int bb = blk >> 6;
  const int s0base = (blk & 63) * TOUT;
  const int ltok = s0base - NWARM + j;

  // stage x -> fp16 LDS (coalesced)
  {
    const float4* xg4 = (const float4*)(x + (size_t)bb * S_ * DIN);
    #pragma unroll
    for (int k = 0; k < 16; ++k) {
      const int f = k * PIPE + j;
      const int tok = f >> 4, c4 = f & 15;
      const int lt = s0base - NWARM + tok;
      float4 v = make_float4(0.f, 0.f, 0.f, 0.f);
      if (lt >= 0) v = xg4[lt * 16 + c4];
      lds[tok * XSTR + 2*c4]     = pack2(v.x, v.y);
      lds[tok * XSTR + 2*c4 + 1] = pack2(v.z, v.w);
    }
  }
  __syncthreads();

  const uint* xrow = lds + j * XSTR;

  // nq0 = g0 + 2 gx.x + x^T G x
  float nq = Wf[OFF_G0];
  nq = fmaf(2.f, dotx(Wh + HOFF_GX, xrow, 0.f), nq);
  #pragma unroll 1
  for (int hh = 0; hh < 2; ++hh) {
    float a2[32];
    #pragma unroll
    for (int n = 0; n < 32; ++n) a2[n] = 0.f;
    #pragma unroll 4
    for (int c2 = 0; c2 < 32; ++c2) {
      const uint xp = xrow[c2];
      const uint* G0 = Wh + HOFF_G + c2*64 + 32*hh;
      #pragma unroll
      for (int n = 0; n < 32; ++n) a2[n] = fdot2h(G0[n], xp, a2[n]);
    }
    float hd = 0.f;
    #pragma unroll
    for (int m = 0; m < 16; ++m) {
      float a, b; unpack2(xrow[16*hh + m], a, b);
      hd = fmaf(a, a2[2*m], hd); hd = fmaf(b, a2[2*m+1], hd);
    }
    nq += hd;
  }

  const uv16 zv = (uv16)0u;
  const uv16 s0v = layer_body<0>(j, ltok, lds, Wf, Wh, Bb, nq, zv,  zv,  zv);
  const uv16 s1v = layer_body<1>(j, ltok, lds, Wf, Wh, Bb, nq, s0v, zv,  zv);
  const uv16 s2v = layer_body<2>(j, ltok, lds, Wf, Wh, Bb, nq, s0v, s1v, zv);
  const uv16 s3v = layer_body<3>(j, ltok, lds, Wf, Wh, Bb, nq, s0v, s1v, s2v);

  const float r = 1.0f / (sqrtf(fmaxf(nq, 0.f)) * 0.0625f + 1e-8f);
  __syncthreads();   // all FIR D-reads done; LDS becomes reduce scratch

  float* pf = (float*)lds;
  const int jj = j - NWARM;

  // pass 0: [r, x0..31 * r]  (x re-read fp32 from global)
  if (j >= NWARM) {
    pf[jj*PSTR] = r;
    const float4* xr4 = (const float4*)(x + ((size_t)bb * S_ + (size_t)ltok) * DIN);
    #pragma unroll
    for (int c4 = 0; c4 < 8; ++c4) {
      const float4 v = xr4[c4];
      pf[jj*PSTR + 1 + 4*c4] = v.x * r; pf[jj*PSTR + 2 + 4*c4] = v.y * r;
      pf[jj*PSTR + 3 + 4*c4] = v.z * r; pf[jj*PSTR + 4 + 4*c4] = v.w * r;
    }
  }
  __syncthreads();
  if (j < 33) { float s = 0.f; for (int k = 0; k < TOUT; ++k) s += pf[k*PSTR + j];
                part[blk*193 + j] = s; }
  __syncthreads();
  // pass 1: x32..63 * r
  if (j >= NWARM) {
    const float4* xr4 = (const float4*)(x + ((size_t)bb * S_ + (size_t)ltok) * DIN);
    #pragma unroll
    for (int c4 = 8; c4 < 16; ++c4) {
      const float4 v = xr4[c4];
      const int o = 4*c4 - 32;
      pf[jj*PSTR + o] = v.x * r; pf[jj*PSTR + o + 1] = v.y * r;
      pf[jj*PSTR + o + 2] = v.z * r; pf[jj*PSTR + o + 3] = v.w * r;
    }
  }
  __syncthreads();
  if (j < 32) { float s = 0.f; for (int k = 0; k < TOUT; ++k) s += pf[k*PSTR + j];
                part[blk*193 + 33 + j] = s; }
  __syncthreads();

  spass(s0v, r, pf, j, jj, part, 65,  blk);
  spass(s1v, r, pf, j, jj, part, 97,  blk);
  spass(s2v, r, pf, j, jj, part, 129, blk);
  spass(s3v, r, pf, j, jj, part, 161, blk);
}

// ---------------------------------------------------------------------------
// Final: reduce partials, reconstruct 256-dim mean, classifier MLP.
// ---------------------------------------------------------------------------
__global__ __launch_bounds__(256) void ssm_final(
    const float* __restrict__ part,
    const float* __restrict__ in_w, const float* __restrict__ in_b,
    const float* __restrict__ Cw, const float* __restrict__ Cb,
    const float* __restrict__ fsc,
    const float* __restrict__ w1, const float* __restrict__ b1,
    const float* __restrict__ w2, const float* __restrict__ b2,
    float* __restrict__ out)
{
  const int b = blockIdx.x, t = threadIdx.x;
  __shared__ float red[193];
  __shared__ float meanv[DM];
  __shared__ float h1[DM];
  if (t < 193) {
    float s = 0.f;
    for (int k = 0; k < 64; ++k) s += part[(b*64 + k)*193 + t];
    red[t] = s;
  }
  __syncthreads();
  {
    const float rho = red[0];
    float m = in_b[t] * rho;
    #pragma unroll 4
    for (int i = 0; i < 64; ++i) m = fmaf(in_w[t*64 + i], red[1 + i], m);
    for (int l = 0; l < NL; ++l) {
      #pragma unroll 4
      for (int n = 0; n < 32; ++n)
        m = fmaf(Cw[(l*DM + t)*NS + n], red[65 + l*32 + n], m);
      m = fmaf(Cb[l*DM + t], rho, m);
    }
    meanv[t] = fsc[t] * m * (1.0f / (float)S_);
  }
  __syncthreads();
  {
    float z = b1[t];
    for (int e = 0; e < DM; ++e) z = fmaf(w1[t*DM + e], meanv[e], z);
    h1[t] = z / (1.0f + expf(-z));
  }
  __syncthreads();
  if (t < 10) {
    float lg = b2[t];
    for (int e = 0; e < DM; ++e) lg = fmaf(w2[t*DM + e], h1[e], lg);
    out[b*10 + t] = lg;
  }
}

// ---------------------------------------------------------------------------
extern "C" void kernel_launch(void* const* d_in, const int* in_sizes, int n_in,
                              void* d_out, int out_size, void* d_ws, size_t ws_size,
                              hipStream_t stream)
{
  const float* x    = (const float*)d_in[0];
  const float* in_w = (const float*)d_in[1];
  const float* in_b = (const float*)d_in[2];
  const float* logA = (const float*)d_in[3];
  const float* Bw   = (const float*)d_in[4];
  const float* Bb   = (const float*)d_in[5];
  const float* Cw   = (const float*)d_in[6];
  const float* Cb   = (const float*)d_in[7];
  const float* nsc  = (const float*)d_in[8];
  const float* fsc  = (const float*)d_in[9];
  const float* w1   = (const float*)d_in[10];
  const float* b1   = (const float*)d_in[11];
  const float* w2   = (const float*)d_in[12];
  const float* b2   = (const float*)d_in[13];
  float* out = (float*)d_out;
  float* wsf  = (float*)d_ws;
  uint*  Wh   = (uint*)(wsf + WS_WH);
  float* part = wsf + WS_PART;
  (void)in_sizes; (void)n_in; (void)out_size; (void)ws_size;

  ssm_prep<<<(PRE_N + 255) / 256, 256, 0, stream>>>(in_w, in_b, logA, Bw, Cw, Cb, nsc, wsf);
  ssm_pack<<<(WH_N + 255) / 256, 256, 0, stream>>>(wsf, Wh);
  ssm_main<<<NBLK, PIPE, LDSN * sizeof(uint), stream>>>(x, wsf, Wh, Bb, part);
  ssm_final<<<B_, 256, 0, stream>>>(part, in_w, in_b, Cw, Cb, fsc, w1, b1, w2, b2, out);
}